// Round 11
// baseline (267.365 us; speedup 1.0000x reference)
//
#include <hip/hip_runtime.h>
#include <hip/hip_bf16.h>

// Problem constants (reference: T=2048, B=2, D_MODEL=1024, H=16, HEAD_DIM=64)
#define TT 2048
#define BB 2
#define CC 1024
#define HH 16
#define DD 64
#define MM (TT * BB)   // 4096 rows in the projection GEMMs

typedef short bf16x8 __attribute__((ext_vector_type(8)));   // 8 bf16 in 4 VGPRs
typedef float f32x4  __attribute__((ext_vector_type(4)));

// float -> bf16 (round-nearest-even), bit-level
__device__ inline ushort f2b(float f) {
    union { float f; unsigned u; } v; v.f = f;
    unsigned r = v.u + 0x7FFFu + ((v.u >> 16) & 1u);
    return (ushort)(r >> 16);
}

// pack 2 floats -> 2 bf16 in one dword
__device__ inline unsigned pack_bf16(float a, float b) {
    __hip_bfloat162 h = __float22bfloat162_rn(make_float2(a, b));
    union { __hip_bfloat162 h; unsigned u; } c; c.h = h;
    return c.u;
}

// async global->LDS, 16B per lane (GEMM staging only)
__device__ inline void gload_lds16(const ushort* g, ushort* l) {
    __builtin_amdgcn_global_load_lds(
        (const __attribute__((address_space(1))) void*)g,
        (__attribute__((address_space(3))) void*)l, 16, 0, 0);
}

// ---------------------------------------------------------------------------
// fp32 -> bf16 convert, x and all four W in one launch.
// ---------------------------------------------------------------------------
#define XQUADS (MM * CC / 4)          // 1048576
#define WQUADS (CC * CC / 4)          // 262144
__global__ __launch_bounds__(256) void conv_all(const float* __restrict__ x,
                                                const float* __restrict__ Wq,
                                                const float* __restrict__ Wk,
                                                const float* __restrict__ Wv,
                                                const float* __restrict__ Wo,
                                                ushort* __restrict__ dst) {
    int idx = blockIdx.x * 256 + threadIdx.x;    // quad index
    const float* src;
    int off;
    if (idx < XQUADS) {
        src = x; off = idx;
    } else {
        int wi = (idx - XQUADS) >> 18;           // WQUADS == 2^18
        off = (idx - XQUADS) & (WQUADS - 1);
        src = (wi == 0) ? Wq : (wi == 1) ? Wk : (wi == 2) ? Wv : Wo;
    }
    float4 v = ((const float4*)src)[off];
    ushort4 o = {f2b(v.x), f2b(v.y), f2b(v.z), f2b(v.w)};
    ((ushort4*)dst)[idx] = o;
}

// ---------------------------------------------------------------------------
// bf16 MFMA NT GEMM (m97 structure), 128x128 tile, BK=32, 4 waves (2x2).
// Fused QKV (grid.y = 24): wsel = by>>3 picks B/out.
//   wsel 0 (Q): (B,H,T,D) bf16, scaled by 1/sqrt(64)*log2(e).
//   wsel 1 (K): FRAGMENT-MAJOR Kf (scalar scatter into per-tile fragment
//               chunks; attention reads lane-contiguous b128).
//   wsel 2 (V): (B,H,T,D) bf16 (transposed+permuted by prep_v).
// ---------------------------------------------------------------------------
__global__ __launch_bounds__(256) void gemm_qkv(const ushort* __restrict__ A,
                                                const ushort* __restrict__ B0,
                                                const ushort* __restrict__ B1,
                                                const ushort* __restrict__ B2,
                                                ushort* __restrict__ Oq,
                                                ushort* __restrict__ Ok,
                                                ushort* __restrict__ Ov) {
    __shared__ __align__(16) ushort As[128 * 32];
    __shared__ __align__(16) ushort Bs[128 * 32];

    const int tid = threadIdx.x;
    const int wave = tid >> 6, lane = tid & 63;
    const int quad = lane >> 4, l16 = lane & 15;
    const int wm = wave >> 1, wn = wave & 1;

    const int bm = blockIdx.x * 128;
    const int by = blockIdx.y;
    const int wsel = by >> 3;
    const ushort* Bp = (wsel == 0) ? B0 : (wsel == 1) ? B1 : B2;
    const int bn = (by & 7) * 128;

    const int srow = lane >> 2;
    const int scol = (lane & 3) * 8;

    f32x4 acc[4][4];
#pragma unroll
    for (int i = 0; i < 4; i++)
#pragma unroll
        for (int j = 0; j < 4; j++) acc[i][j] = (f32x4){0.f, 0.f, 0.f, 0.f};

    for (int k0 = 0; k0 < CC; k0 += 32) {
#pragma unroll
        for (int i = 0; i < 2; i++) {
            const int rbase = wave * 32 + i * 16;
            gload_lds16(A + (size_t)(bm + rbase + srow) * CC + k0 + scol,
                        As + rbase * 32);
            gload_lds16(Bp + (size_t)(bn + rbase + srow) * CC + k0 + scol,
                        Bs + rbase * 32);
        }
        __syncthreads();

        bf16x8 af[4], bf[4];
#pragma unroll
        for (int mi = 0; mi < 4; mi++)
            af[mi] = *(const bf16x8*)(As + (wm * 64 + mi * 16 + l16) * 32 + quad * 8);
#pragma unroll
        for (int ni = 0; ni < 4; ni++)
            bf[ni] = *(const bf16x8*)(Bs + (wn * 64 + ni * 16 + l16) * 32 + quad * 8);
#pragma unroll
        for (int mi = 0; mi < 4; mi++)
#pragma unroll
            for (int ni = 0; ni < 4; ni++)
                acc[mi][ni] = __builtin_amdgcn_mfma_f32_16x16x32_bf16(
                    af[mi], bf[ni], acc[mi][ni], 0, 0, 0);
        __syncthreads();
    }

#pragma unroll
    for (int mi = 0; mi < 4; mi++) {
#pragma unroll
        for (int r = 0; r < 4; r++) {
            const int m = bm + wm * 64 + mi * 16 + quad * 4 + r;
#pragma unroll
            for (int ni = 0; ni < 4; ni++) {
                const int colg = bn + wn * 64 + ni * 16 + l16;
                float v = acc[mi][ni][r];
                const int t = m >> 1, b = m & 1;
                const int h = colg >> 6, d = colg & 63;
                if (wsel == 0) {
                    v *= 0.18033688f;  // 1/sqrt(64) * log2(e)
                    Oq[(((size_t)(b * HH + h)) * TT + t) * DD + d] = f2b(v);
                } else if (wsel == 1) {
                    const int jj = t & 63;
                    size_t idx = ((size_t)(b * HH + h) * TT) * DD
                               + (size_t)(t >> 6) * 4096
                               + (d >> 5) * 2048 + (jj >> 4) * 512
                               + (((d >> 3) & 3) * 16 + (jj & 15)) * 8 + (d & 7);
                    Ok[idx] = f2b(v);
                } else {
                    Ov[(((size_t)(b * HH + h)) * TT + t) * DD + d] = f2b(v);
                }
            }
        }
    }
}

// ---------------------------------------------------------------------------
// Out-projection GEMM: 128x64 tile (512 blocks = 2/CU), BK=32, fp32 output.
// ---------------------------------------------------------------------------
__global__ __launch_bounds__(256) void gemm_out(const ushort* __restrict__ A,
                                                const ushort* __restrict__ Bm,
                                                float* __restrict__ Of) {
    __shared__ __align__(16) ushort As[128 * 32];   // 8 KB
    __shared__ __align__(16) ushort Bs[64 * 32];    // 4 KB

    const int tid = threadIdx.x;
    const int wave = tid >> 6, lane = tid & 63;
    const int quad = lane >> 4, l16 = lane & 15;

    const int bm = blockIdx.x * 128;
    const int bn = blockIdx.y * 64;

    const int srow = lane >> 2;
    const int scol = (lane & 3) * 8;

    f32x4 acc[2][4];
#pragma unroll
    for (int i = 0; i < 2; i++)
#pragma unroll
        for (int j = 0; j < 4; j++) acc[i][j] = (f32x4){0.f, 0.f, 0.f, 0.f};

    for (int k0 = 0; k0 < CC; k0 += 32) {
#pragma unroll
        for (int i = 0; i < 2; i++) {
            const int rbase = wave * 32 + i * 16;
            gload_lds16(A + (size_t)(bm + rbase + srow) * CC + k0 + scol,
                        As + rbase * 32);
        }
        gload_lds16(Bm + (size_t)(bn + wave * 16 + srow) * CC + k0 + scol,
                    Bs + wave * 16 * 32);
        __syncthreads();

        bf16x8 af[2], bf[4];
#pragma unroll
        for (int mi = 0; mi < 2; mi++)
            af[mi] = *(const bf16x8*)(As + (wave * 32 + mi * 16 + l16) * 32 + quad * 8);
#pragma unroll
        for (int ni = 0; ni < 4; ni++)
            bf[ni] = *(const bf16x8*)(Bs + (ni * 16 + l16) * 32 + quad * 8);
#pragma unroll
        for (int mi = 0; mi < 2; mi++)
#pragma unroll
            for (int ni = 0; ni < 4; ni++)
                acc[mi][ni] = __builtin_amdgcn_mfma_f32_16x16x32_bf16(
                    af[mi], bf[ni], acc[mi][ni], 0, 0, 0);
        __syncthreads();
    }

#pragma unroll
    for (int mi = 0; mi < 2; mi++)
#pragma unroll
        for (int r = 0; r < 4; r++) {
            const int m = bm + wave * 32 + mi * 16 + quad * 4 + r;
#pragma unroll
            for (int ni = 0; ni < 4; ni++)
                Of[(size_t)m * CC + bn + ni * 16 + l16] = acc[mi][ni][r];
        }
}

// ---------------------------------------------------------------------------
// prep_v: V (B,H,T,D) -> fragment-major Vf per 64-key tile:
//   Vf[tile chunk o = c*256+db*64+lane][u] = V[j][d=db*16+(lane&15)],
//   j' = c*32+(lane>>4)*8+u, j = (j'&3)*16 + (j'>>2)   (packed-P permutation).
// ---------------------------------------------------------------------------
__global__ __launch_bounds__(256) void prep_v(const ushort* __restrict__ Vb,
                                              ushort* __restrict__ Vf) {
    __shared__ __align__(16) ushort Ls[64 * 72];
    const int tile = blockIdx.x;      // 0..31
    const int bh   = blockIdx.y;
    const int t    = threadIdx.x;
    const size_t src = (size_t)bh * TT * DD + (size_t)tile * 64 * DD;
    const size_t dst = (size_t)bh * TT * DD + (size_t)tile * 4096;

#pragma unroll
    for (int i = 0; i < 2; i++) {
        int e = t + i * 256;
        int r = e >> 3, kc = (e & 7) * 8;
        *(uint4*)(Ls + r * 72 + kc) = *(const uint4*)(Vb + src + r * 64 + kc);
    }
    __syncthreads();
#pragma unroll
    for (int i = 0; i < 2; i++) {
        int o = t + i * 256;
        int c = o >> 8, db = (o >> 6) & 3, lane = o & 63;
        int quad = lane >> 4, l16 = lane & 15;
        int d = db * 16 + l16;
        ushort tmp[8];
#pragma unroll
        for (int u = 0; u < 8; u++) {
            int jp = c * 32 + quad * 8 + u;
            int j = (jp & 3) * 16 + (jp >> 2);
            tmp[u] = Ls[j * 72 + d];
        }
        *(uint4*)(Vf + dst + (size_t)o * 8) = *(uint4*)tmp;
    }
}

// ---------------------------------------------------------------------------
// Flash step, one 64-key tile vs one wave's 16 queries (register fragments).
// Max-free softmax: p = exp2(s) (Q pre-scaled by 0.125*log2e).
// ---------------------------------------------------------------------------
template <bool DIAG>
__device__ __forceinline__ void attn_step(const bf16x8* qa, f32x4* O, float* l,
                                          const bf16x8* kf, const bf16x8* vf,
                                          ushort* P, int j0, int qbase,
                                          int quad, int l16) {
    f32x4 S[4];
#pragma unroll
    for (int nb = 0; nb < 4; nb++) S[nb] = (f32x4){0.f, 0.f, 0.f, 0.f};
#pragma unroll
    for (int c = 0; c < 2; c++)
#pragma unroll
        for (int nb = 0; nb < 4; nb++)
            S[nb] = __builtin_amdgcn_mfma_f32_16x16x32_bf16(qa[c], kf[c * 4 + nb],
                                                            S[nb], 0, 0, 0);

#pragma unroll
    for (int r = 0; r < 4; r++) {
        const int qg = qbase + quad * 4 + r;
        float p[4];
#pragma unroll
        for (int nb = 0; nb < 4; nb++) {
            float s = S[nb][r];
            if (DIAG) { if (j0 + nb * 16 + l16 > qg) s = -1e30f; }
            p[nb] = __builtin_amdgcn_exp2f(s);
        }
        l[r] += (p[0] + p[1]) + (p[2] + p[3]);
        uint2 w; w.x = pack_bf16(p[0], p[1]); w.y = pack_bf16(p[2], p[3]);
        *(uint2*)(P + (quad * 4 + r) * 72 + l16 * 4) = w;
    }

#pragma unroll
    for (int c = 0; c < 2; c++) {
        bf16x8 pa = *(const bf16x8*)(P + l16 * 72 + c * 32 + quad * 8);
#pragma unroll
        for (int db = 0; db < 4; db++)
            O[db] = __builtin_amdgcn_mfma_f32_16x16x32_bf16(pa, vf[c * 4 + db],
                                                            O[db], 0, 0, 0);
    }
}

// ---------------------------------------------------------------------------
// Split-K paired-tile flash MFMA attention. Block (p, kp) handles q-tiles
// p and 31-p with k-tiles kt = kp, kp+2, ... (stride 2). Grid (32, 32) =
// 1024 blocks = 4/CU = 16 waves/CU — 2x the occupancy of the 512-block form.
// Max-free softmax makes split-K additive: O = O0+O1, l = l0+l1 (combined
// and normalized by attn_combine). NO barriers in the k-loop.
// ---------------------------------------------------------------------------
__global__ __launch_bounds__(256, 4) void attn_mfma(const ushort* __restrict__ Qb,
                                                    const ushort* __restrict__ Kf,
                                                    const ushort* __restrict__ Vf,
                                                    float* __restrict__ Opart,
                                                    float* __restrict__ Lpart) {
    __shared__ __align__(16) ushort PsA[4 * 16 * 72];   // per-wave P_A[m][j']
    __shared__ __align__(16) ushort PsB[4 * 16 * 72];   // per-wave P_B[m][j']

    const int tid  = threadIdx.x;
    const int wave = tid >> 6;
    const int lane = tid & 63;
    const int quad = lane >> 4;
    const int l16  = lane & 15;

    const int bx = blockIdx.x;                    // 0..31
    const int p  = bx >> 1;                       // pair index 0..15
    const int kp = bx & 1;                        // split-K half
    const int bh = blockIdx.y;
    const int qtA = p, qtB = 31 - p;              // qtA < 16 <= qtB
    const int q0A = qtA * 64 + wave * 16;
    const int q0B = qtB * 64 + wave * 16;

    const size_t baseQK = (size_t)bh * TT * DD;

    bf16x8 qaA[2], qaB[2];
    {
        const ushort* qp = Qb + baseQK + (size_t)(q0A + l16) * DD + quad * 8;
        qaA[0] = *(const bf16x8*)(qp);
        qaA[1] = *(const bf16x8*)(qp + 32);
        const ushort* qp2 = Qb + baseQK + (size_t)(q0B + l16) * DD + quad * 8;
        qaB[0] = *(const bf16x8*)(qp2);
        qaB[1] = *(const bf16x8*)(qp2 + 32);
    }

    f32x4 OA[4], OB[4];
#pragma unroll
    for (int i = 0; i < 4; i++) {
        OA[i] = (f32x4){0.f, 0.f, 0.f, 0.f};
        OB[i] = (f32x4){0.f, 0.f, 0.f, 0.f};
    }
    float lA[4] = {0.f, 0.f, 0.f, 0.f};
    float lB[4] = {0.f, 0.f, 0.f, 0.f};

    ushort* PA = PsA + wave * 16 * 72;
    ushort* PB = PsB + wave * 16 * 72;

    const ushort* Kfb = Kf + baseQK;
    const ushort* Vfb = Vf + baseQK;

    for (int kt = kp; kt <= qtB; kt += 2) {
        const int j0 = kt * 64;
        const ushort* Kfp = Kfb + ((size_t)kt << 12);
        const ushort* Vfp = Vfb + ((size_t)kt << 12);

        bf16x8 kf[8], vf[8];
#pragma unroll
        for (int i = 0; i < 8; i++) {
            kf[i] = *(const bf16x8*)(Kfp + (i << 9) + lane * 8);
            vf[i] = *(const bf16x8*)(Vfp + (i << 9) + lane * 8);
        }

        if (kt == qtB)
            attn_step<true >(qaB, OB, lB, kf, vf, PB, j0, q0B, quad, l16);
        else
            attn_step<false>(qaB, OB, lB, kf, vf, PB, j0, q0B, quad, l16);

        if (kt < qtA)
            attn_step<false>(qaA, OA, lA, kf, vf, PA, j0, q0A, quad, l16);
        else if (kt == qtA)
            attn_step<true >(qaA, OA, lA, kf, vf, PA, j0, q0A, quad, l16);
    }

    // ---- epilogue: write partial O (fp32) and partial l per q-row ----
    const size_t obA = (((size_t)bh * 32 + qtA) * 2 + kp) * 4096;
    const size_t obB = (((size_t)bh * 32 + qtB) * 2 + kp) * 4096;
    const size_t lbA = (((size_t)bh * 32 + qtA) * 2 + kp) * 64;
    const size_t lbB = (((size_t)bh * 32 + qtB) * 2 + kp) * 64;
#pragma unroll
    for (int r = 0; r < 4; r++) {
        const int row = wave * 16 + quad * 4 + r;
        float la = lA[r], lb = lB[r];
        la += __shfl_xor(la, 1); la += __shfl_xor(la, 2);
        la += __shfl_xor(la, 4); la += __shfl_xor(la, 8);
        lb += __shfl_xor(lb, 1); lb += __shfl_xor(lb, 2);
        lb += __shfl_xor(lb, 4); lb += __shfl_xor(lb, 8);
        if (l16 == 0) {
            Lpart[lbA + row] = la;
            Lpart[lbB + row] = lb;
        }
#pragma unroll
        for (int db = 0; db < 4; db++) {
            Opart[obA + (size_t)row * 64 + db * 16 + l16] = OA[db][r];
            Opart[obB + (size_t)row * 64 + db * 16 + l16] = OB[db][r];
        }
    }
}

// ---------------------------------------------------------------------------
// Combine the two split-K partials, normalize, write ctx (T,B,C) bf16.
// Grid (32 q-tiles, 32 bh), 256 threads; thread handles one (row, 16-col) run.
// ---------------------------------------------------------------------------
__global__ __launch_bounds__(256) void attn_combine(const float* __restrict__ Opart,
                                                    const float* __restrict__ Lpart,
                                                    ushort* __restrict__ ctx) {
    const int qt = blockIdx.x;
    const int bh = blockIdx.y;
    const int tid = threadIdx.x;
    const int row = tid >> 2;           // 0..63
    const int cg  = (tid & 3) * 16;     // column group

    const size_t b0 = (((size_t)bh * 32 + qt) * 2 + 0) * 4096;
    const size_t b1 = b0 + 4096;
    const size_t l0 = (((size_t)bh * 32 + qt) * 2 + 0) * 64;

    const float l = Lpart[l0 + row] + Lpart[l0 + 64 + row];
    const float inv = 1.f / l;

    float4 o0[4], o1[4];
#pragma unroll
    for (int i = 0; i < 4; i++) {
        o0[i] = *(const float4*)(Opart + b0 + (size_t)row * 64 + cg + i * 4);
        o1[i] = *(const float4*)(Opart + b1 + (size_t)row * 64 + cg + i * 4);
    }

    ushort tmp[16];
#pragma unroll
    for (int i = 0; i < 4; i++) {
        tmp[i * 4 + 0] = f2b((o0[i].x + o1[i].x) * inv);
        tmp[i * 4 + 1] = f2b((o0[i].y + o1[i].y) * inv);
        tmp[i * 4 + 2] = f2b((o0[i].z + o1[i].z) * inv);
        tmp[i * 4 + 3] = f2b((o0[i].w + o1[i].w) * inv);
    }

    const int t = qt * 64 + row;
    const int b = bh >> 4, h = bh & 15;
    ushort* dst = ctx + ((size_t)t * BB + b) * CC + h * DD + cg;
    *(uint4*)(dst)     = *(uint4*)(tmp);
    *(uint4*)(dst + 8) = *(uint4*)(tmp + 8);
}

// ---------------------------------------------------------------------------
extern "C" void kernel_launch(void* const* d_in, const int* in_sizes, int n_in,
                              void* d_out, int out_size, void* d_ws, size_t ws_size,
                              hipStream_t stream) {
    const float* x  = (const float*)d_in[0];
    const float* Wq = (const float*)d_in[1];
    const float* Wk = (const float*)d_in[2];
    const float* Wv = (const float*)d_in[3];
    const float* Wo = (const float*)d_in[4];
    float* out = (float*)d_out;

    // Workspace: xb|Wb|Qb|Kf|Vb|Vf|Ctxb (bf16, 8MB each) + Opart 33.5MB + Lpart
    ushort* xb  = (ushort*)d_ws;
    ushort* Wb  = xb + (size_t)MM * CC;
    ushort* Wqb = Wb;
    ushort* Wkb = Wb + (size_t)CC * CC;
    ushort* Wvb = Wb + 2 * (size_t)CC * CC;
    ushort* Wob = Wb + 3 * (size_t)CC * CC;
    ushort* Qb  = Wb + 4 * (size_t)CC * CC;
    ushort* Kf  = Qb + (size_t)MM * CC;
    ushort* Vb  = Kf + (size_t)MM * CC;
    ushort* Vf  = Vb + (size_t)MM * CC;
    ushort* Ctxb = Vf + (size_t)MM * CC;
    float*  Opart = (float*)(Ctxb + (size_t)MM * CC);
    float*  Lpart = Opart + (size_t)32 * 32 * 2 * 4096;   // 8.39M floats
    // total ~93 MB

    conv_all<<<dim3((XQUADS + 4 * WQUADS) / 256), 256, 0, stream>>>(
        x, Wq, Wk, Wv, Wo, xb);

    gemm_qkv<<<dim3(MM / 128, 24), 256, 0, stream>>>(
        xb, Wqb, Wkb, Wvb, Qb, Kf, Vb);

    prep_v<<<dim3(TT / 64, BB * HH), 256, 0, stream>>>(Vb, Vf);

    attn_mfma<<<dim3(32, BB * HH), 256, 0, stream>>>(Qb, Kf, Vf, Opart, Lpart);

    attn_combine<<<dim3(TT / 64, BB * HH), 256, 0, stream>>>(Opart, Lpart, Ctxb);

    gemm_out<<<dim3(MM / 128, CC / 64), 256, 0, stream>>>(Ctxb, Wob, out);
}

// Round 12
// 181.418 us; speedup vs baseline: 1.4738x; 1.4738x over previous
//
#include <hip/hip_runtime.h>
#include <hip/hip_bf16.h>

// Problem constants (reference: T=2048, B=2, D_MODEL=1024, H=16, HEAD_DIM=64)
#define TT 2048
#define BB 2
#define CC 1024
#define HH 16
#define DD 64
#define MM (TT * BB)   // 4096 rows in the projection GEMMs

typedef short bf16x8 __attribute__((ext_vector_type(8)));   // 8 bf16 in 4 VGPRs
typedef float f32x4  __attribute__((ext_vector_type(4)));

// float -> bf16 (round-nearest-even), bit-level
__device__ inline ushort f2b(float f) {
    union { float f; unsigned u; } v; v.f = f;
    unsigned r = v.u + 0x7FFFu + ((v.u >> 16) & 1u);
    return (ushort)(r >> 16);
}

// pack 2 floats -> 2 bf16 in one dword
__device__ inline unsigned pack_bf16(float a, float b) {
    __hip_bfloat162 h = __float22bfloat162_rn(make_float2(a, b));
    union { __hip_bfloat162 h; unsigned u; } c; c.h = h;
    return c.u;
}

// async global->LDS, 16B per lane (GEMM staging only)
__device__ inline void gload_lds16(const ushort* g, ushort* l) {
    __builtin_amdgcn_global_load_lds(
        (const __attribute__((address_space(1))) void*)g,
        (__attribute__((address_space(3))) void*)l, 16, 0, 0);
}

// ---------------------------------------------------------------------------
// fp32 -> bf16 convert, x and all four W in one launch.
// ---------------------------------------------------------------------------
#define XQUADS (MM * CC / 4)          // 1048576
#define WQUADS (CC * CC / 4)          // 262144
__global__ __launch_bounds__(256) void conv_all(const float* __restrict__ x,
                                                const float* __restrict__ Wq,
                                                const float* __restrict__ Wk,
                                                const float* __restrict__ Wv,
                                                const float* __restrict__ Wo,
                                                ushort* __restrict__ dst) {
    int idx = blockIdx.x * 256 + threadIdx.x;    // quad index
    const float* src;
    int off;
    if (idx < XQUADS) {
        src = x; off = idx;
    } else {
        int wi = (idx - XQUADS) >> 18;           // WQUADS == 2^18
        off = (idx - XQUADS) & (WQUADS - 1);
        src = (wi == 0) ? Wq : (wi == 1) ? Wk : (wi == 2) ? Wv : Wo;
    }
    float4 v = ((const float4*)src)[off];
    ushort4 o = {f2b(v.x), f2b(v.y), f2b(v.z), f2b(v.w)};
    ((ushort4*)dst)[idx] = o;
}

// ---------------------------------------------------------------------------
// bf16 MFMA NT GEMM (m97 structure), 128x128 tile, BK=32, 4 waves (2x2).
// Fused QKV (grid.y = 24): wsel = by>>3 picks B/out.
//   wsel 0 (Q): (B,H,T,D) bf16, scaled by 1/sqrt(64)*log2(e).
//   wsel 1 (K): FRAGMENT-MAJOR Kf (scalar scatter into per-tile fragment
//               chunks; attention reads lane-contiguous b128).
//   wsel 2 (V): (B,H,T,D) bf16 (transposed+permuted by prep_v).
// ---------------------------------------------------------------------------
__global__ __launch_bounds__(256) void gemm_qkv(const ushort* __restrict__ A,
                                                const ushort* __restrict__ B0,
                                                const ushort* __restrict__ B1,
                                                const ushort* __restrict__ B2,
                                                ushort* __restrict__ Oq,
                                                ushort* __restrict__ Ok,
                                                ushort* __restrict__ Ov) {
    __shared__ __align__(16) ushort As[128 * 32];
    __shared__ __align__(16) ushort Bs[128 * 32];

    const int tid = threadIdx.x;
    const int wave = tid >> 6, lane = tid & 63;
    const int quad = lane >> 4, l16 = lane & 15;
    const int wm = wave >> 1, wn = wave & 1;

    const int bm = blockIdx.x * 128;
    const int by = blockIdx.y;
    const int wsel = by >> 3;
    const ushort* Bp = (wsel == 0) ? B0 : (wsel == 1) ? B1 : B2;
    const int bn = (by & 7) * 128;

    const int srow = lane >> 2;
    const int scol = (lane & 3) * 8;

    f32x4 acc[4][4];
#pragma unroll
    for (int i = 0; i < 4; i++)
#pragma unroll
        for (int j = 0; j < 4; j++) acc[i][j] = (f32x4){0.f, 0.f, 0.f, 0.f};

    for (int k0 = 0; k0 < CC; k0 += 32) {
#pragma unroll
        for (int i = 0; i < 2; i++) {
            const int rbase = wave * 32 + i * 16;
            gload_lds16(A + (size_t)(bm + rbase + srow) * CC + k0 + scol,
                        As + rbase * 32);
            gload_lds16(Bp + (size_t)(bn + rbase + srow) * CC + k0 + scol,
                        Bs + rbase * 32);
        }
        __syncthreads();

        bf16x8 af[4], bf[4];
#pragma unroll
        for (int mi = 0; mi < 4; mi++)
            af[mi] = *(const bf16x8*)(As + (wm * 64 + mi * 16 + l16) * 32 + quad * 8);
#pragma unroll
        for (int ni = 0; ni < 4; ni++)
            bf[ni] = *(const bf16x8*)(Bs + (wn * 64 + ni * 16 + l16) * 32 + quad * 8);
#pragma unroll
        for (int mi = 0; mi < 4; mi++)
#pragma unroll
            for (int ni = 0; ni < 4; ni++)
                acc[mi][ni] = __builtin_amdgcn_mfma_f32_16x16x32_bf16(
                    af[mi], bf[ni], acc[mi][ni], 0, 0, 0);
        __syncthreads();
    }

#pragma unroll
    for (int mi = 0; mi < 4; mi++) {
#pragma unroll
        for (int r = 0; r < 4; r++) {
            const int m = bm + wm * 64 + mi * 16 + quad * 4 + r;
#pragma unroll
            for (int ni = 0; ni < 4; ni++) {
                const int colg = bn + wn * 64 + ni * 16 + l16;
                float v = acc[mi][ni][r];
                const int t = m >> 1, b = m & 1;
                const int h = colg >> 6, d = colg & 63;
                if (wsel == 0) {
                    v *= 0.18033688f;  // 1/sqrt(64) * log2(e)
                    Oq[(((size_t)(b * HH + h)) * TT + t) * DD + d] = f2b(v);
                } else if (wsel == 1) {
                    const int jj = t & 63;
                    size_t idx = ((size_t)(b * HH + h) * TT) * DD
                               + (size_t)(t >> 6) * 4096
                               + (d >> 5) * 2048 + (jj >> 4) * 512
                               + (((d >> 3) & 3) * 16 + (jj & 15)) * 8 + (d & 7);
                    Ok[idx] = f2b(v);
                } else {
                    Ov[(((size_t)(b * HH + h)) * TT + t) * DD + d] = f2b(v);
                }
            }
        }
    }
}

// ---------------------------------------------------------------------------
// Out-projection GEMM: 128x64 tile (512 blocks = 2/CU), BK=32, fp32 output.
// ---------------------------------------------------------------------------
__global__ __launch_bounds__(256) void gemm_out(const ushort* __restrict__ A,
                                                const ushort* __restrict__ Bm,
                                                float* __restrict__ Of) {
    __shared__ __align__(16) ushort As[128 * 32];   // 8 KB
    __shared__ __align__(16) ushort Bs[64 * 32];    // 4 KB

    const int tid = threadIdx.x;
    const int wave = tid >> 6, lane = tid & 63;
    const int quad = lane >> 4, l16 = lane & 15;

    const int bm = blockIdx.x * 128;
    const int bn = blockIdx.y * 64;

    const int srow = lane >> 2;
    const int scol = (lane & 3) * 8;

    f32x4 acc[2][4];
#pragma unroll
    for (int i = 0; i < 2; i++)
#pragma unroll
        for (int j = 0; j < 4; j++) acc[i][j] = (f32x4){0.f, 0.f, 0.f, 0.f};

    for (int k0 = 0; k0 < CC; k0 += 32) {
#pragma unroll
        for (int i = 0; i < 2; i++) {
            const int rbase = wave * 32 + i * 16;
            gload_lds16(A + (size_t)(bm + rbase + srow) * CC + k0 + scol,
                        As + rbase * 32);
        }
        gload_lds16(Bm + (size_t)(bn + wave * 16 + srow) * CC + k0 + scol,
                    Bs + wave * 16 * 32);
        __syncthreads();

        bf16x8 af[2], bf[4];
#pragma unroll
        for (int mi = 0; mi < 2; mi++)
            af[mi] = *(const bf16x8*)(As + (wave * 32 + mi * 16 + l16) * 32 + quad * 8);
#pragma unroll
        for (int ni = 0; ni < 4; ni++)
            bf[ni] = *(const bf16x8*)(Bs + (ni * 16 + l16) * 32 + quad * 8);
#pragma unroll
        for (int mi = 0; mi < 2; mi++)
#pragma unroll
            for (int ni = 0; ni < 4; ni++)
                acc[mi][ni] = __builtin_amdgcn_mfma_f32_16x16x32_bf16(
                    af[mi], bf[ni], acc[mi][ni], 0, 0, 0);
        __syncthreads();
    }

#pragma unroll
    for (int mi = 0; mi < 2; mi++)
#pragma unroll
        for (int r = 0; r < 4; r++) {
            const int m = bm + wave * 32 + mi * 16 + quad * 4 + r;
#pragma unroll
            for (int ni = 0; ni < 4; ni++)
                Of[(size_t)m * CC + bn + ni * 16 + l16] = acc[mi][ni][r];
        }
}

// ---------------------------------------------------------------------------
// prep_v: V (B,H,T,D) -> fragment-major Vf per 64-key tile:
//   Vf[tile chunk o = c*256+db*64+lane][u] = V[j][d=db*16+(lane&15)],
//   j' = c*32+(lane>>4)*8+u, j = (j'&3)*16 + (j'>>2)   (packed-P permutation).
// ---------------------------------------------------------------------------
__global__ __launch_bounds__(256) void prep_v(const ushort* __restrict__ Vb,
                                              ushort* __restrict__ Vf) {
    __shared__ __align__(16) ushort Ls[64 * 72];
    const int tile = blockIdx.x;      // 0..31
    const int bh   = blockIdx.y;
    const int t    = threadIdx.x;
    const size_t src = (size_t)bh * TT * DD + (size_t)tile * 64 * DD;
    const size_t dst = (size_t)bh * TT * DD + (size_t)tile * 4096;

#pragma unroll
    for (int i = 0; i < 2; i++) {
        int e = t + i * 256;
        int r = e >> 3, kc = (e & 7) * 8;
        *(uint4*)(Ls + r * 72 + kc) = *(const uint4*)(Vb + src + r * 64 + kc);
    }
    __syncthreads();
#pragma unroll
    for (int i = 0; i < 2; i++) {
        int o = t + i * 256;
        int c = o >> 8, db = (o >> 6) & 3, lane = o & 63;
        int quad = lane >> 4, l16 = lane & 15;
        int d = db * 16 + l16;
        ushort tmp[8];
#pragma unroll
        for (int u = 0; u < 8; u++) {
            int jp = c * 32 + quad * 8 + u;
            int j = (jp & 3) * 16 + (jp >> 2);
            tmp[u] = Ls[j * 72 + d];
        }
        *(uint4*)(Vf + dst + (size_t)o * 8) = *(uint4*)tmp;
    }
}

// ---------------------------------------------------------------------------
// Flash step, one 64-key tile vs one wave's 16 queries (register fragments).
// Max-free softmax: p = exp2(s) (Q pre-scaled by 0.125*log2e).
// ---------------------------------------------------------------------------
template <bool DIAG>
__device__ __forceinline__ void attn_step(const bf16x8* qa, f32x4* O, float* l,
                                          const bf16x8* kf, const bf16x8* vf,
                                          ushort* P, int j0, int qbase,
                                          int quad, int l16) {
    f32x4 S[4];
#pragma unroll
    for (int nb = 0; nb < 4; nb++) S[nb] = (f32x4){0.f, 0.f, 0.f, 0.f};
#pragma unroll
    for (int c = 0; c < 2; c++)
#pragma unroll
        for (int nb = 0; nb < 4; nb++)
            S[nb] = __builtin_amdgcn_mfma_f32_16x16x32_bf16(qa[c], kf[c * 4 + nb],
                                                            S[nb], 0, 0, 0);

#pragma unroll
    for (int r = 0; r < 4; r++) {
        const int qg = qbase + quad * 4 + r;
        float p[4];
#pragma unroll
        for (int nb = 0; nb < 4; nb++) {
            float s = S[nb][r];
            if (DIAG) { if (j0 + nb * 16 + l16 > qg) s = -1e30f; }
            p[nb] = __builtin_amdgcn_exp2f(s);
        }
        l[r] += (p[0] + p[1]) + (p[2] + p[3]);
        uint2 w; w.x = pack_bf16(p[0], p[1]); w.y = pack_bf16(p[2], p[3]);
        *(uint2*)(P + (quad * 4 + r) * 72 + l16 * 4) = w;
    }

#pragma unroll
    for (int c = 0; c < 2; c++) {
        bf16x8 pa = *(const bf16x8*)(P + l16 * 72 + c * 32 + quad * 8);
#pragma unroll
        for (int db = 0; db < 4; db++)
            O[db] = __builtin_amdgcn_mfma_f32_16x16x32_bf16(pa, vf[c * 4 + db],
                                                            O[db], 0, 0, 0);
    }
}

// ---------------------------------------------------------------------------
// Paired-tile flash MFMA attention (R8 geometry + register prefetch):
// block p handles q-tiles p and 31-p (uniform 33 tile-visits), grid
// (16, BB*HH) = 512 blocks = 2/CU. K/V fragment-major in global — each
// fragment load is lane-contiguous 1KB b128, L1-shared by the block's 4
// waves. Next tile's fragments are prefetched into registers during compute
// on the current tile (hides L1/L2 vmcnt latency). NO barriers in the
// k-loop; LDS = wave-private P buffers only.
// ---------------------------------------------------------------------------
__global__ __launch_bounds__(256, 2) void attn_mfma(const ushort* __restrict__ Qb,
                                                    const ushort* __restrict__ Kf,
                                                    const ushort* __restrict__ Vf,
                                                    ushort* __restrict__ ctx) {
    __shared__ __align__(16) ushort PsA[4 * 16 * 72];   // per-wave P_A[m][j']
    __shared__ __align__(16) ushort PsB[4 * 16 * 72];   // per-wave P_B[m][j']

    const int tid  = threadIdx.x;
    const int wave = tid >> 6;
    const int lane = tid & 63;
    const int quad = lane >> 4;
    const int l16  = lane & 15;

    const int p  = blockIdx.x;                    // 0..15
    const int bh = blockIdx.y;
    const int qtA = p, qtB = (TT / 64 - 1) - p;   // qtA < 16 <= qtB
    const int q0A = qtA * 64 + wave * 16;
    const int q0B = qtB * 64 + wave * 16;

    const size_t baseQK = (size_t)bh * TT * DD;

    bf16x8 qaA[2], qaB[2];
    {
        const ushort* qp = Qb + baseQK + (size_t)(q0A + l16) * DD + quad * 8;
        qaA[0] = *(const bf16x8*)(qp);
        qaA[1] = *(const bf16x8*)(qp + 32);
        const ushort* qp2 = Qb + baseQK + (size_t)(q0B + l16) * DD + quad * 8;
        qaB[0] = *(const bf16x8*)(qp2);
        qaB[1] = *(const bf16x8*)(qp2 + 32);
    }

    f32x4 OA[4], OB[4];
#pragma unroll
    for (int i = 0; i < 4; i++) {
        OA[i] = (f32x4){0.f, 0.f, 0.f, 0.f};
        OB[i] = (f32x4){0.f, 0.f, 0.f, 0.f};
    }
    float lA[4] = {0.f, 0.f, 0.f, 0.f};
    float lB[4] = {0.f, 0.f, 0.f, 0.f};

    ushort* PA = PsA + wave * 16 * 72;
    ushort* PB = PsB + wave * 16 * 72;

    const ushort* Kfp = Kf + baseQK;   // +4096 elements per 64-key tile
    const ushort* Vfp = Vf + baseQK;

    // prefetch tile 0 fragments
    bf16x8 kf[8], vf[8], kn[8], vn[8];
#pragma unroll
    for (int i = 0; i < 8; i++) {
        kf[i] = *(const bf16x8*)(Kfp + (i << 9) + lane * 8);
        vf[i] = *(const bf16x8*)(Vfp + (i << 9) + lane * 8);
    }

    for (int kt = 0; kt <= qtB; kt++) {
        const int j0 = kt * 64;

        // issue next tile's fragment loads (latency overlaps compute below)
        if (kt < qtB) {
            const ushort* Kn = Kfp + (((size_t)kt + 1) << 12);
            const ushort* Vn = Vfp + (((size_t)kt + 1) << 12);
#pragma unroll
            for (int i = 0; i < 8; i++) {
                kn[i] = *(const bf16x8*)(Kn + (i << 9) + lane * 8);
                vn[i] = *(const bf16x8*)(Vn + (i << 9) + lane * 8);
            }
        }

        if (kt == qtB)
            attn_step<true >(qaB, OB, lB, kf, vf, PB, j0, q0B, quad, l16);
        else
            attn_step<false>(qaB, OB, lB, kf, vf, PB, j0, q0B, quad, l16);

        if (kt < qtA)
            attn_step<false>(qaA, OA, lA, kf, vf, PA, j0, q0A, quad, l16);
        else if (kt == qtA)
            attn_step<true >(qaA, OA, lA, kf, vf, PA, j0, q0A, quad, l16);

#pragma unroll
        for (int i = 0; i < 8; i++) { kf[i] = kn[i]; vf[i] = vn[i]; }
    }

    // epilogue: row-reduce l across 16-lane groups, normalize, store bf16
    const int b = bh >> 4, h = bh & 15;
#pragma unroll
    for (int r = 0; r < 4; r++) {
        float la = lA[r], lb = lB[r];
        la += __shfl_xor(la, 1); la += __shfl_xor(la, 2);
        la += __shfl_xor(la, 4); la += __shfl_xor(la, 8);
        lb += __shfl_xor(lb, 1); lb += __shfl_xor(lb, 2);
        lb += __shfl_xor(lb, 4); lb += __shfl_xor(lb, 8);
        const float invA = 1.f / la;
        const float invB = 1.f / lb;
        const int tA = q0A + quad * 4 + r;
        const int tB = q0B + quad * 4 + r;
#pragma unroll
        for (int db = 0; db < 4; db++) {
            ctx[((size_t)tA * BB + b) * CC + h * DD + db * 16 + l16] =
                f2b(OA[db][r] * invA);
            ctx[((size_t)tB * BB + b) * CC + h * DD + db * 16 + l16] =
                f2b(OB[db][r] * invB);
        }
    }
}

// ---------------------------------------------------------------------------
extern "C" void kernel_launch(void* const* d_in, const int* in_sizes, int n_in,
                              void* d_out, int out_size, void* d_ws, size_t ws_size,
                              hipStream_t stream) {
    const float* x  = (const float*)d_in[0];
    const float* Wq = (const float*)d_in[1];
    const float* Wk = (const float*)d_in[2];
    const float* Wv = (const float*)d_in[3];
    const float* Wo = (const float*)d_in[4];
    float* out = (float*)d_out;

    // Workspace (bf16): xb 8MB | Wb 8MB | Qb 8 | Kf 8 | Vb 8 | Vf 8 | Ctxb 8 = 56MB
    ushort* xb  = (ushort*)d_ws;
    ushort* Wb  = xb + (size_t)MM * CC;
    ushort* Wqb = Wb;
    ushort* Wkb = Wb + (size_t)CC * CC;
    ushort* Wvb = Wb + 2 * (size_t)CC * CC;
    ushort* Wob = Wb + 3 * (size_t)CC * CC;
    ushort* Qb  = Wb + 4 * (size_t)CC * CC;
    ushort* Kf  = Qb + (size_t)MM * CC;
    ushort* Vb  = Kf + (size_t)MM * CC;
    ushort* Vf  = Vb + (size_t)MM * CC;
    ushort* Ctxb = Vf + (size_t)MM * CC;

    conv_all<<<dim3((XQUADS + 4 * WQUADS) / 256), 256, 0, stream>>>(
        x, Wq, Wk, Wv, Wo, xb);

    gemm_qkv<<<dim3(MM / 128, 24), 256, 0, stream>>>(
        xb, Wqb, Wkb, Wvb, Qb, Kf, Vb);

    prep_v<<<dim3(TT / 64, BB * HH), 256, 0, stream>>>(Vb, Vf);

    attn_mfma<<<dim3(16, BB * HH), 256, 0, stream>>>(Qb, Kf, Vf, Ctxb);

    gemm_out<<<dim3(MM / 128, CC / 64), 256, 0, stream>>>(Ctxb, Wob, out);
}